// Round 2
// baseline (60.026 us; speedup 1.0000x reference)
//
#include <hip/hip_runtime.h>
#include <math.h>

#define HW 128
#define EPSF 1e-4f
#define L2E 1.4426950408889634f
#define NPART 16            // partial-groups
#define WPB 8               // waves per accum block
#define NGROUPS (NPART * WPB)   // 128 splat groups
#define NP 8                // pixel rows per lane
#define NTILES 32           // 2 col-halves x 16 row-bands

typedef float f2 __attribute__((ext_vector_type(2)));

__device__ __forceinline__ float ex2(float x) {        // 2^x
    float r; asm("v_exp_f32 %0, %1" : "=v"(r) : "v"(x)); return r;
}
__device__ __forceinline__ float rcp_(float x) {       // 1/x
    float r; asm("v_rcp_f32 %0, %1" : "=v"(r) : "v"(x)); return r;
}
__device__ __forceinline__ float fsig(float x) {       // sigmoid
    return rcp_(1.0f + ex2(-L2E * x));
}
__device__ __forceinline__ float ftanh(float x) {      // tanh = 1 - 2/(e^2x+1)
    return 1.0f - 2.0f * rcp_(1.0f + ex2((2.0f * L2E) * x));
}

// One WAVE per splat (4 splats / 256-thr block). Computes polynomial coeffs
// of z*log2e = u0 x^2 + u1 y^2 + u2 xy + u3 x + u4 y + u5 (logdet/log2pi
// cancel in exp(k - k.max())), grid max m via per-column y-vertex, stores
//   tab[n][col] = (qb, qc - m),  qb = u2 x + u4,  qc = (u0 x + u3)x + u5
// and 5 per-splat uniforms SoA-blocked per splat-group for accum s_load:
//   urec[g*spw*5 + {0..4}*spw + o] = {u1, c0, c1, c2, c3}
// Pad splats (n >= n_splats): qc' = -16384 -> exp2 == 0, uniforms = 0.
// Also zeroes the NTILES last-arrival counters used by the fused combine
// (stream order setup->accum makes the zeros visible before any atomicAdd).
__global__ __launch_bounds__(256) void splat_setup_max(
    const float* __restrict__ rho, const float* __restrict__ sigma,
    const float* __restrict__ coords, const float* __restrict__ alpha,
    const float* __restrict__ colors, const float* __restrict__ tm,
    float2* __restrict__ tab, float* __restrict__ urec,
    unsigned* __restrict__ cnt, int n_splats, int nsp_pad)
{
    if (blockIdx.x == 0 && threadIdx.x < NTILES) cnt[threadIdx.x] = 0u;

    const int lane = threadIdx.x & 63;
    const int n = blockIdx.x * 4 + (threadIdx.x >> 6);
    if (n >= nsp_pad) return;

    const int spw = nsp_pad >> 7;              // nsp_pad / NGROUPS
    const int g   = n / spw;
    const int o   = n - g * spw;
    float* ub = urec + (size_t)g * spw * 5;

    if (n >= n_splats) {                       // zero-contribution pad record
        tab[(size_t)n * HW + lane]      = make_float2(0.0f, -16384.0f);
        tab[(size_t)n * HW + 64 + lane] = make_float2(0.0f, -16384.0f);
        if (lane == 0) {
#pragma unroll
            for (int i = 0; i < 5; ++i) ub[i * spw + o] = 0.0f;
        }
        return;
    }

    float T[16];
#pragma unroll
    for (int i = 0; i < 16; ++i) T[i] = tm[i];

    const float a  = fsig(alpha[n]);
    const float r  = fsig(rho[n]) + EPSF;
    const float s0 = fsig(-sigma[n * 3 + 0]);
    const float s1 = fsig(-sigma[n * 3 + 1]);
    const float s2 = fsig(-sigma[n * 3 + 2]);
    const float sx = T[0] * s0 + T[1] * s1 + T[2]  * s2 + T[3];
    const float sy = T[4] * s0 + T[5] * s1 + T[6]  * s2 + T[7];
    const float sz = T[8] * s0 + T[9] * s1 + T[10] * s2 + T[11];

    const float c0 = ftanh(coords[n * 3 + 0]) + 0.5f;
    const float c1 = ftanh(coords[n * 3 + 1]) + 0.5f;
    const float c2 = ftanh(coords[n * 3 + 2]) + 0.5f;
    const float cx = T[0] * c0 + T[1] * c1 + T[2]  * c2 + T[3];
    const float cy = T[4] * c0 + T[5] * c1 + T[6]  * c2 + T[7];
    const float cz = T[8] * c0 + T[9] * c1 + T[10] * c2 + T[11];

    const float col0 = ftanh(colors[n * 4 + 0] * a);
    const float col1 = ftanh(colors[n * 4 + 1] * a);
    const float col2 = ftanh(colors[n * 4 + 2] * a);
    const float col3 = ftanh(colors[n * 4 + 3] * a);

    const float M00 = sx * sx + EPSF, M01 = sx * sy * r, M02 = sx * sz * r;
    const float M11 = sy * sy + EPSF, M12 = sy * sz * r, M22 = sz * sz + EPSF;

    const float C00 = M11 * M22 - M12 * M12;
    const float C01 = M02 * M12 - M01 * M22;
    const float C02 = M01 * M12 - M02 * M11;
    const float det = M00 * C00 + M01 * C01 + M02 * C02;
    const float idet = -0.5f / det;
    const float A00 = C00 * idet;
    const float A01 = C01 * idet;
    const float A02 = C02 * idet;
    const float A11 = (M00 * M22 - M02 * M02) * idet;
    const float A12 = (M01 * M02 - M00 * M12) * idet;
    const float A22 = (M00 * M11 - M01 * M01) * idet;

    const float pz = cz + 1.0f;
    const float u0 = A00 * L2E;
    const float u1 = A11 * L2E;
    const float u2 = 2.0f * A01 * L2E;
    const float u3 = 2.0f * (A00 * cx + A01 * cy + A02 * pz) * L2E;
    const float u4 = 2.0f * (A01 * cx + A11 * cy + A12 * pz) * L2E;
    const float u5 = (A00 * cx * cx + A11 * cy * cy + A22 * pz * pz
                      + 2.0f * (A01 * cx * cy + A02 * cx * pz + A12 * cy * pz)) * L2E;

    float qbv[2], qcv[2];
    float m = -INFINITY;
#pragma unroll
    for (int cc = 0; cc < 2; ++cc) {
        const int colx = lane + 64 * cc;
        const float x  = (float)colx * (1.0f / HW);
        const float qb = fmaf(u2, x, u4);
        const float qc = fmaf(fmaf(u0, x, u3), x, u5);
        qbv[cc] = qb; qcv[cc] = qc;
        const float yv = -qb * 0.5f * rcp_(u1);
        int iy = (int)rintf(yv * (float)HW);
        iy = max(1, min(HW - 2, iy));
        const int cand[5] = {0, HW - 1, iy - 1, iy, iy + 1};
#pragma unroll
        for (int q = 0; q < 5; ++q) {
            const float y = (float)cand[q] * (1.0f / HW);
            m = fmaxf(m, fmaf(fmaf(u1, y, qb), y, qc));
        }
    }
#pragma unroll
    for (int off = 32; off > 0; off >>= 1)
        m = fmaxf(m, __shfl_xor(m, off, 64));

    tab[(size_t)n * HW + lane]      = make_float2(qbv[0], qcv[0] - m);
    tab[(size_t)n * HW + 64 + lane] = make_float2(qbv[1], qcv[1] - m);
    if (lane == 0) {
        ub[0 * spw + o] = u1;
        ub[1 * spw + o] = col0;
        ub[2 * spw + o] = col1;
        ub[3 * spw + o] = col2;
        ub[4 * spw + o] = col3;
    }
}

// 512 blocks (32 pixel-tiles x 16 partial-groups) x 512 thr (8 waves),
// launch_bounds(512,4) -> 4 waves/SIMD, VGPR <= 128. Tile: col-half
// ch = tile&1 (lane -> column ch*64+lane), row-band rb = tile>>1 (rows
// rb*8+{0..7}). Wave w streams splat group pg*8+w (16 splats). Uniforms
// hoisted to SGPRs before the loop. Inner loop: ONE coalesced per-lane
// dwordx2 tab load per splat feeding 8 pixels, and PACKED fp32 math
// (v_pk_fma_f32 on row-pairs; SGPR coefficients broadcast free in VOP3P).
// Tail: 3-round LDS tree, partial store; then FUSED split-K combine:
// wave0 release-fences (cross-XCD L2 writeback) + atomicAdd on the tile
// counter; the 16th arriving block acquire-fences and sums the NPART
// partials (same gg order as the old combine kernel -> bit-identical),
// writing out directly. Last-arrival pattern: no waiting, no dispatch-
// order or co-residency assumptions (G16-safe).
__global__ __launch_bounds__(512, 4) void splat_accum(
    const float2* __restrict__ tab, const float* __restrict__ urec,
    float4* __restrict__ part, float4* __restrict__ out,
    unsigned* __restrict__ cnt, int nsp_pad)
{
    __shared__ float4 lred[4][NP][64];        // 32 KB
    __shared__ int lastFlag;

    const int t    = threadIdx.x;
    const int lane = t & 63;
    const int w    = __builtin_amdgcn_readfirstlane(t >> 6);   // wave 0..7
    const int tile = blockIdx.x >> 4;         // 0..31
    const int pg   = blockIdx.x & 15;         // partial-group
    const int g    = pg * WPB + w;            // splat group 0..127 (scalar)

    const int ch      = tile & 1;
    const int rowBand = tile >> 1;            // 0..15
    const int col     = ch * 64 + lane;

    f2 yv2[NP / 2], y22[NP / 2];
#pragma unroll
    for (int i = 0; i < NP / 2; ++i) {
        const float ya = (float)(rowBand * NP + 2 * i)     * (1.0f / HW);
        const float yb = (float)(rowBand * NP + 2 * i + 1) * (1.0f / HW);
        yv2[i] = (f2){ya, yb};
        y22[i] = (f2){ya * ya, yb * yb};
    }

    const int spw = nsp_pad >> 7;             // 16 for N=2048
    const int j0  = g * spw;

    f2 acc[4][NP / 2];                        // [channel][row-pair]
#pragma unroll
    for (int c = 0; c < 4; ++c)
#pragma unroll
        for (int i = 0; i < NP / 2; ++i) acc[c][i] = (f2){0.0f, 0.0f};

    const f2*    tp = (const f2*)(tab + (size_t)j0 * HW + col);
    const float* gb = urec + (size_t)g * spw * 5;   // uniform (scalar) ptr

    if (spw == 16) {
        float su1[16], sc0[16], sc1[16], sc2[16], sc3[16];
#pragma unroll
        for (int j = 0; j < 16; ++j) {
            su1[j] = gb[j];
            sc0[j] = gb[16 + j];
            sc1[j] = gb[32 + j];
            sc2[j] = gb[48 + j];
            sc3[j] = gb[64 + j];
        }
#pragma unroll
        for (int j = 0; j < 16; ++j) {
            const f2 q = tp[(size_t)j * HW];  // (qb, qc')
#pragma unroll
            for (int i = 0; i < NP / 2; ++i) {
                f2 z = su1[j] * y22[i] + q.y; // pk_fma, SGPR+bcast operands
                z = q.x * yv2[i] + z;         // pk_fma
                const f2 w2 = (f2){ex2(z.x), ex2(z.y)};
                acc[0][i] = w2 * sc0[j] + acc[0][i];   // pk_fma, SGPR bcast
                acc[1][i] = w2 * sc1[j] + acc[1][i];
                acc[2][i] = w2 * sc2[j] + acc[2][i];
                acc[3][i] = w2 * sc3[j] + acc[3][i];
            }
        }
    } else {
        for (int j = 0; j < spw; ++j) {
            const f2 q = tp[(size_t)j * HW];
            const float u1j = gb[j];
            const float c0j = gb[spw + j];
            const float c1j = gb[2 * spw + j];
            const float c2j = gb[3 * spw + j];
            const float c3j = gb[4 * spw + j];
#pragma unroll
            for (int i = 0; i < NP / 2; ++i) {
                f2 z = u1j * y22[i] + q.y;
                z = q.x * yv2[i] + z;
                const f2 w2 = (f2){ex2(z.x), ex2(z.y)};
                acc[0][i] = w2 * c0j + acc[0][i];
                acc[1][i] = w2 * c1j + acc[1][i];
                acc[2][i] = w2 * c2j + acc[2][i];
                acc[3][i] = w2 * c3j + acc[3][i];
            }
        }
    }

    // unpack to per-pixel float4 for the reduction tail
    float4 vout[NP];
#pragma unroll
    for (int p = 0; p < NP; ++p) {
        const int i = p >> 1;
        if (p & 1) vout[p] = make_float4(acc[0][i].y, acc[1][i].y, acc[2][i].y, acc[3][i].y);
        else       vout[p] = make_float4(acc[0][i].x, acc[1][i].x, acc[2][i].x, acc[3][i].x);
    }

    // 3-round tree: 8 waves -> 1
    if (w >= 4) {
#pragma unroll
        for (int p = 0; p < NP; ++p) lred[w - 4][p][lane] = vout[p];
    }
    __syncthreads();
    if (w < 4) {
#pragma unroll
        for (int p = 0; p < NP; ++p) {
            const float4 v = lred[w][p][lane];
            vout[p].x += v.x; vout[p].y += v.y; vout[p].z += v.z; vout[p].w += v.w;
        }
    }
    __syncthreads();
    if (w == 2 || w == 3) {
#pragma unroll
        for (int p = 0; p < NP; ++p) lred[w - 2][p][lane] = vout[p];
    }
    __syncthreads();
    if (w < 2) {
#pragma unroll
        for (int p = 0; p < NP; ++p) {
            const float4 v = lred[w][p][lane];
            vout[p].x += v.x; vout[p].y += v.y; vout[p].z += v.z; vout[p].w += v.w;
        }
    }
    __syncthreads();
    if (w == 1) {
#pragma unroll
        for (int p = 0; p < NP; ++p) lred[0][p][lane] = vout[p];
    }
    __syncthreads();
    if (w == 0) {
#pragma unroll
        for (int p = 0; p < NP; ++p) {
            const float4 v = lred[0][p][lane];
            vout[p].x += v.x; vout[p].y += v.y; vout[p].z += v.z; vout[p].w += v.w;
            part[(size_t)pg * (HW * HW) + (rowBand * NP + p) * HW + col] = vout[p];
        }
    }

    // ---- fused split-K combine (last-arrival) ----
    __syncthreads();                          // all waves; w0 stores issued
    if (w == 0) {
        __threadfence();                      // agent release: vmcnt drain + L2 wb
        if (lane == 0) {
            const unsigned old = atomicAdd(&cnt[tile], 1u);   // device scope
            lastFlag = (old == NPART - 1) ? 1 : 0;
        }
    }
    __syncthreads();
    if (lastFlag) {
        __threadfence();                      // agent acquire: invalidate caches
        const int px   = t;                   // 0..511 = 8 rows x 64 cols
        const int row  = rowBand * NP + (px >> 6);
        const int colp = ch * 64 + (px & 63);
        const size_t pix = (size_t)row * HW + colp;
        float4 s = part[pix];                 // gg = 0
#pragma unroll
        for (int gg = 1; gg < NPART; ++gg) {
            const float4 v = part[(size_t)gg * (HW * HW) + pix];
            s.x += v.x; s.y += v.y; s.z += v.z; s.w += v.w;
        }
        out[pix] = s;
    }
}

extern "C" void kernel_launch(void* const* d_in, const int* in_sizes, int n_in,
                              void* d_out, int out_size, void* d_ws, size_t ws_size,
                              hipStream_t stream) {
    const float* rho    = (const float*)d_in[0];
    const float* sigma  = (const float*)d_in[1];
    const float* coords = (const float*)d_in[2];
    const float* alpha  = (const float*)d_in[3];
    const float* colors = (const float*)d_in[4];
    const float* tm     = (const float*)d_in[5];

    const int n_splats = in_sizes[0];
    const int nsp_pad  = (n_splats + 511) & ~511;   // %512==0

    // workspace layout (256 B aligned):
    //   tab  : nsp_pad * 128 * float2
    //   urec : nsp_pad * 5 * float (SoA-blocked per group)
    //   part : NPART * 16384 * float4
    //   cnt  : NTILES * u32 (last-arrival counters, zeroed by setup)
    char* wsb = (char*)d_ws;
    float2* tab = (float2*)wsb;
    size_t off = ((size_t)nsp_pad * HW * sizeof(float2) + 255) & ~(size_t)255;
    float* urec = (float*)(wsb + off);
    off = (off + (size_t)nsp_pad * 5 * sizeof(float) + 255) & ~(size_t)255;
    float4* part = (float4*)(wsb + off);
    off = (off + (size_t)NPART * (HW * HW) * sizeof(float4) + 255) & ~(size_t)255;
    unsigned* cnt = (unsigned*)(wsb + off);

    splat_setup_max<<<nsp_pad / 4, 256, 0, stream>>>(
        rho, sigma, coords, alpha, colors, tm, tab, urec, cnt, n_splats, nsp_pad);
    splat_accum<<<32 * NPART, 512, 0, stream>>>(
        tab, urec, part, (float4*)d_out, cnt, nsp_pad);
}

// Round 3
// 25.911 us; speedup vs baseline: 2.3166x; 2.3166x over previous
//
#include <hip/hip_runtime.h>
#include <math.h>

#define HW 128
#define EPSF 1e-4f
#define L2E 1.4426950408889634f
#define NPART 16            // partial-groups
#define WPB 8               // waves per accum block
#define NGROUPS (NPART * WPB)   // 128 splat groups
#define NP 8                // pixel rows per lane
#define NTILES 32           // 2 col-halves x 16 row-bands

typedef float f2 __attribute__((ext_vector_type(2)));

__device__ __forceinline__ float ex2(float x) {        // 2^x
    float r; asm("v_exp_f32 %0, %1" : "=v"(r) : "v"(x)); return r;
}
__device__ __forceinline__ float rcp_(float x) {       // 1/x
    float r; asm("v_rcp_f32 %0, %1" : "=v"(r) : "v"(x)); return r;
}
__device__ __forceinline__ float fsig(float x) {       // sigmoid
    return rcp_(1.0f + ex2(-L2E * x));
}
__device__ __forceinline__ float ftanh(float x) {      // tanh = 1 - 2/(e^2x+1)
    return 1.0f - 2.0f * rcp_(1.0f + ex2((2.0f * L2E) * x));
}

// Agent-scope write-through helpers: relaxed atomics compile to plain
// global_store/load with sc1 (bypass XCD L2, coherence point = MALL).
// NO fence instructions, NO buffer_wbl2/inv — that was round-2's 60 us.
__device__ __forceinline__ void st_agent_f4(float4* p, float4 v) {
    union { float4 f; unsigned long long u[2]; } cv; cv.f = v;
    unsigned long long* q = (unsigned long long*)p;
    __hip_atomic_store(q,     cv.u[0], __ATOMIC_RELAXED, __HIP_MEMORY_SCOPE_AGENT);
    __hip_atomic_store(q + 1, cv.u[1], __ATOMIC_RELAXED, __HIP_MEMORY_SCOPE_AGENT);
}
__device__ __forceinline__ float4 ld_agent_f4(const float4* p) {
    union { float4 f; unsigned long long u[2]; } cv;
    const unsigned long long* q = (const unsigned long long*)p;
    cv.u[0] = __hip_atomic_load(q,     __ATOMIC_RELAXED, __HIP_MEMORY_SCOPE_AGENT);
    cv.u[1] = __hip_atomic_load(q + 1, __ATOMIC_RELAXED, __HIP_MEMORY_SCOPE_AGENT);
    return cv.f;
}

// One WAVE per splat (4 splats / 256-thr block). Computes polynomial coeffs
// of z*log2e = u0 x^2 + u1 y^2 + u2 xy + u3 x + u4 y + u5 (logdet/log2pi
// cancel in exp(k - k.max())), grid max m via per-column y-vertex, stores
//   tab[n][col] = (qb, qc - m),  qb = u2 x + u4,  qc = (u0 x + u3)x + u5
// and 5 per-splat uniforms SoA-blocked per splat-group for accum s_load:
//   urec[g*spw*5 + {0..4}*spw + o] = {u1, c0, c1, c2, c3}
// Pad splats (n >= n_splats): qc' = -16384 -> exp2 == 0, uniforms = 0.
// Also zeroes the NTILES last-arrival counters (visible to accum's atomics
// via the implicit release/acquire at the dispatch boundary — validated r2).
__global__ __launch_bounds__(256) void splat_setup_max(
    const float* __restrict__ rho, const float* __restrict__ sigma,
    const float* __restrict__ coords, const float* __restrict__ alpha,
    const float* __restrict__ colors, const float* __restrict__ tm,
    float2* __restrict__ tab, float* __restrict__ urec,
    unsigned* __restrict__ cnt, int n_splats, int nsp_pad)
{
    if (blockIdx.x == 0 && threadIdx.x < NTILES) cnt[threadIdx.x] = 0u;

    const int lane = threadIdx.x & 63;
    const int n = blockIdx.x * 4 + (threadIdx.x >> 6);
    if (n >= nsp_pad) return;

    const int spw = nsp_pad >> 7;              // nsp_pad / NGROUPS
    const int g   = n / spw;
    const int o   = n - g * spw;
    float* ub = urec + (size_t)g * spw * 5;

    if (n >= n_splats) {                       // zero-contribution pad record
        tab[(size_t)n * HW + lane]      = make_float2(0.0f, -16384.0f);
        tab[(size_t)n * HW + 64 + lane] = make_float2(0.0f, -16384.0f);
        if (lane == 0) {
#pragma unroll
            for (int i = 0; i < 5; ++i) ub[i * spw + o] = 0.0f;
        }
        return;
    }

    float T[16];
#pragma unroll
    for (int i = 0; i < 16; ++i) T[i] = tm[i];

    const float a  = fsig(alpha[n]);
    const float r  = fsig(rho[n]) + EPSF;
    const float s0 = fsig(-sigma[n * 3 + 0]);
    const float s1 = fsig(-sigma[n * 3 + 1]);
    const float s2 = fsig(-sigma[n * 3 + 2]);
    const float sx = T[0] * s0 + T[1] * s1 + T[2]  * s2 + T[3];
    const float sy = T[4] * s0 + T[5] * s1 + T[6]  * s2 + T[7];
    const float sz = T[8] * s0 + T[9] * s1 + T[10] * s2 + T[11];

    const float c0 = ftanh(coords[n * 3 + 0]) + 0.5f;
    const float c1 = ftanh(coords[n * 3 + 1]) + 0.5f;
    const float c2 = ftanh(coords[n * 3 + 2]) + 0.5f;
    const float cx = T[0] * c0 + T[1] * c1 + T[2]  * c2 + T[3];
    const float cy = T[4] * c0 + T[5] * c1 + T[6]  * c2 + T[7];
    const float cz = T[8] * c0 + T[9] * c1 + T[10] * c2 + T[11];

    const float col0 = ftanh(colors[n * 4 + 0] * a);
    const float col1 = ftanh(colors[n * 4 + 1] * a);
    const float col2 = ftanh(colors[n * 4 + 2] * a);
    const float col3 = ftanh(colors[n * 4 + 3] * a);

    const float M00 = sx * sx + EPSF, M01 = sx * sy * r, M02 = sx * sz * r;
    const float M11 = sy * sy + EPSF, M12 = sy * sz * r, M22 = sz * sz + EPSF;

    const float C00 = M11 * M22 - M12 * M12;
    const float C01 = M02 * M12 - M01 * M22;
    const float C02 = M01 * M12 - M02 * M11;
    const float det = M00 * C00 + M01 * C01 + M02 * C02;
    const float idet = -0.5f / det;
    const float A00 = C00 * idet;
    const float A01 = C01 * idet;
    const float A02 = C02 * idet;
    const float A11 = (M00 * M22 - M02 * M02) * idet;
    const float A12 = (M01 * M02 - M00 * M12) * idet;
    const float A22 = (M00 * M11 - M01 * M01) * idet;

    const float pz = cz + 1.0f;
    const float u0 = A00 * L2E;
    const float u1 = A11 * L2E;
    const float u2 = 2.0f * A01 * L2E;
    const float u3 = 2.0f * (A00 * cx + A01 * cy + A02 * pz) * L2E;
    const float u4 = 2.0f * (A01 * cx + A11 * cy + A12 * pz) * L2E;
    const float u5 = (A00 * cx * cx + A11 * cy * cy + A22 * pz * pz
                      + 2.0f * (A01 * cx * cy + A02 * cx * pz + A12 * cy * pz)) * L2E;

    float qbv[2], qcv[2];
    float m = -INFINITY;
#pragma unroll
    for (int cc = 0; cc < 2; ++cc) {
        const int colx = lane + 64 * cc;
        const float x  = (float)colx * (1.0f / HW);
        const float qb = fmaf(u2, x, u4);
        const float qc = fmaf(fmaf(u0, x, u3), x, u5);
        qbv[cc] = qb; qcv[cc] = qc;
        const float yv = -qb * 0.5f * rcp_(u1);
        int iy = (int)rintf(yv * (float)HW);
        iy = max(1, min(HW - 2, iy));
        const int cand[5] = {0, HW - 1, iy - 1, iy, iy + 1};
#pragma unroll
        for (int q = 0; q < 5; ++q) {
            const float y = (float)cand[q] * (1.0f / HW);
            m = fmaxf(m, fmaf(fmaf(u1, y, qb), y, qc));
        }
    }
#pragma unroll
    for (int off = 32; off > 0; off >>= 1)
        m = fmaxf(m, __shfl_xor(m, off, 64));

    tab[(size_t)n * HW + lane]      = make_float2(qbv[0], qcv[0] - m);
    tab[(size_t)n * HW + 64 + lane] = make_float2(qbv[1], qcv[1] - m);
    if (lane == 0) {
        ub[0 * spw + o] = u1;
        ub[1 * spw + o] = col0;
        ub[2 * spw + o] = col1;
        ub[3 * spw + o] = col2;
        ub[4 * spw + o] = col3;
    }
}

// 512 blocks (32 pixel-tiles x 16 partial-groups) x 512 thr (8 waves),
// launch_bounds(512,4) -> 4 waves/SIMD, VGPR <= 128. Main loop identical
// to the proven 20.9us version (pk_fma math, SGPR-hoisted uniforms, one
// dwordx2 tab load / splat feeding 8 pixels). Tail: 3-round LDS tree,
// then FUSED split-K combine with WRITE-THROUGH coherence (no fences):
//   wave0 stores its partial via sc1 (agent-relaxed) stores -> MALL,
//   s_waitcnt vmcnt(0)  (wait-only; NOT a cache flush),
//   lane0 atomicAdd on the tile counter (relaxed, agent),
//   16th arrival reads all NPART partials via sc1 loads (bypass L1/L2,
//   no invalidate needed) and sums in the same gg order as the old
//   combine kernel -> bit-identical output.
__global__ __launch_bounds__(512, 4) void splat_accum(
    const float2* __restrict__ tab, const float* __restrict__ urec,
    float4* __restrict__ part, float4* __restrict__ out,
    unsigned* __restrict__ cnt, int nsp_pad)
{
    __shared__ float4 lred[4][NP][64];        // 32 KB
    __shared__ int lastFlag;

    const int t    = threadIdx.x;
    const int lane = t & 63;
    const int w    = __builtin_amdgcn_readfirstlane(t >> 6);   // wave 0..7
    const int tile = blockIdx.x >> 4;         // 0..31
    const int pg   = blockIdx.x & 15;         // partial-group
    const int g    = pg * WPB + w;            // splat group 0..127 (scalar)

    const int ch      = tile & 1;
    const int rowBand = tile >> 1;            // 0..15
    const int col     = ch * 64 + lane;

    f2 yv2[NP / 2], y22[NP / 2];
#pragma unroll
    for (int i = 0; i < NP / 2; ++i) {
        const float ya = (float)(rowBand * NP + 2 * i)     * (1.0f / HW);
        const float yb = (float)(rowBand * NP + 2 * i + 1) * (1.0f / HW);
        yv2[i] = (f2){ya, yb};
        y22[i] = (f2){ya * ya, yb * yb};
    }

    const int spw = nsp_pad >> 7;             // 16 for N=2048
    const int j0  = g * spw;

    f2 acc[4][NP / 2];                        // [channel][row-pair]
#pragma unroll
    for (int c = 0; c < 4; ++c)
#pragma unroll
        for (int i = 0; i < NP / 2; ++i) acc[c][i] = (f2){0.0f, 0.0f};

    const f2*    tp = (const f2*)(tab + (size_t)j0 * HW + col);
    const float* gb = urec + (size_t)g * spw * 5;   // uniform (scalar) ptr

    if (spw == 16) {
        float su1[16], sc0[16], sc1[16], sc2[16], sc3[16];
#pragma unroll
        for (int j = 0; j < 16; ++j) {
            su1[j] = gb[j];
            sc0[j] = gb[16 + j];
            sc1[j] = gb[32 + j];
            sc2[j] = gb[48 + j];
            sc3[j] = gb[64 + j];
        }
#pragma unroll
        for (int j = 0; j < 16; ++j) {
            const f2 q = tp[(size_t)j * HW];  // (qb, qc')
#pragma unroll
            for (int i = 0; i < NP / 2; ++i) {
                f2 z = su1[j] * y22[i] + q.y; // pk_fma, SGPR+bcast operands
                z = q.x * yv2[i] + z;         // pk_fma
                const f2 w2 = (f2){ex2(z.x), ex2(z.y)};
                acc[0][i] = w2 * sc0[j] + acc[0][i];   // pk_fma, SGPR bcast
                acc[1][i] = w2 * sc1[j] + acc[1][i];
                acc[2][i] = w2 * sc2[j] + acc[2][i];
                acc[3][i] = w2 * sc3[j] + acc[3][i];
            }
        }
    } else {
        for (int j = 0; j < spw; ++j) {
            const f2 q = tp[(size_t)j * HW];
            const float u1j = gb[j];
            const float c0j = gb[spw + j];
            const float c1j = gb[2 * spw + j];
            const float c2j = gb[3 * spw + j];
            const float c3j = gb[4 * spw + j];
#pragma unroll
            for (int i = 0; i < NP / 2; ++i) {
                f2 z = u1j * y22[i] + q.y;
                z = q.x * yv2[i] + z;
                const f2 w2 = (f2){ex2(z.x), ex2(z.y)};
                acc[0][i] = w2 * c0j + acc[0][i];
                acc[1][i] = w2 * c1j + acc[1][i];
                acc[2][i] = w2 * c2j + acc[2][i];
                acc[3][i] = w2 * c3j + acc[3][i];
            }
        }
    }

    // unpack to per-pixel float4 for the reduction tail
    float4 vout[NP];
#pragma unroll
    for (int p = 0; p < NP; ++p) {
        const int i = p >> 1;
        if (p & 1) vout[p] = make_float4(acc[0][i].y, acc[1][i].y, acc[2][i].y, acc[3][i].y);
        else       vout[p] = make_float4(acc[0][i].x, acc[1][i].x, acc[2][i].x, acc[3][i].x);
    }

    // 3-round tree: 8 waves -> 1
    if (w >= 4) {
#pragma unroll
        for (int p = 0; p < NP; ++p) lred[w - 4][p][lane] = vout[p];
    }
    __syncthreads();
    if (w < 4) {
#pragma unroll
        for (int p = 0; p < NP; ++p) {
            const float4 v = lred[w][p][lane];
            vout[p].x += v.x; vout[p].y += v.y; vout[p].z += v.z; vout[p].w += v.w;
        }
    }
    __syncthreads();
    if (w == 2 || w == 3) {
#pragma unroll
        for (int p = 0; p < NP; ++p) lred[w - 2][p][lane] = vout[p];
    }
    __syncthreads();
    if (w < 2) {
#pragma unroll
        for (int p = 0; p < NP; ++p) {
            const float4 v = lred[w][p][lane];
            vout[p].x += v.x; vout[p].y += v.y; vout[p].z += v.z; vout[p].w += v.w;
        }
    }
    __syncthreads();
    if (w == 1) {
#pragma unroll
        for (int p = 0; p < NP; ++p) lred[0][p][lane] = vout[p];
    }
    __syncthreads();
    if (w == 0) {
#pragma unroll
        for (int p = 0; p < NP; ++p) {
            const float4 v = lred[0][p][lane];
            vout[p].x += v.x; vout[p].y += v.y; vout[p].z += v.z; vout[p].w += v.w;
            st_agent_f4(&part[(size_t)pg * (HW * HW) + (rowBand * NP + p) * HW + col],
                        vout[p]);
        }
        // wait-only drain: sc1 stores acked at the coherence point before
        // the arrival atomic can be observed. No cache maintenance.
        asm volatile("s_waitcnt vmcnt(0)" ::: "memory");
        if (lane == 0) {
            const unsigned old = atomicAdd(&cnt[tile], 1u);   // relaxed, agent
            lastFlag = (old == NPART - 1) ? 1 : 0;
        }
    }
    __syncthreads();
    if (lastFlag) {
        const int row  = rowBand * NP + (t >> 6);
        const int colp = ch * 64 + (t & 63);
        const size_t pix = (size_t)row * HW + colp;
        float4 s = ld_agent_f4(&part[pix]);   // gg = 0
#pragma unroll
        for (int gg = 1; gg < NPART; ++gg) {
            const float4 v = ld_agent_f4(&part[(size_t)gg * (HW * HW) + pix]);
            s.x += v.x; s.y += v.y; s.z += v.z; s.w += v.w;
        }
        out[pix] = s;
    }
}

extern "C" void kernel_launch(void* const* d_in, const int* in_sizes, int n_in,
                              void* d_out, int out_size, void* d_ws, size_t ws_size,
                              hipStream_t stream) {
    const float* rho    = (const float*)d_in[0];
    const float* sigma  = (const float*)d_in[1];
    const float* coords = (const float*)d_in[2];
    const float* alpha  = (const float*)d_in[3];
    const float* colors = (const float*)d_in[4];
    const float* tm     = (const float*)d_in[5];

    const int n_splats = in_sizes[0];
    const int nsp_pad  = (n_splats + 511) & ~511;   // %512==0

    // workspace layout (256 B aligned):
    //   tab  : nsp_pad * 128 * float2
    //   urec : nsp_pad * 5 * float (SoA-blocked per group)
    //   part : NPART * 16384 * float4
    //   cnt  : NTILES * u32 (last-arrival counters, zeroed by setup)
    char* wsb = (char*)d_ws;
    float2* tab = (float2*)wsb;
    size_t off = ((size_t)nsp_pad * HW * sizeof(float2) + 255) & ~(size_t)255;
    float* urec = (float*)(wsb + off);
    off = (off + (size_t)nsp_pad * 5 * sizeof(float) + 255) & ~(size_t)255;
    float4* part = (float4*)(wsb + off);
    off = (off + (size_t)NPART * (HW * HW) * sizeof(float4) + 255) & ~(size_t)255;
    unsigned* cnt = (unsigned*)(wsb + off);

    splat_setup_max<<<nsp_pad / 4, 256, 0, stream>>>(
        rho, sigma, coords, alpha, colors, tm, tab, urec, cnt, n_splats, nsp_pad);
    splat_accum<<<32 * NPART, 512, 0, stream>>>(
        tab, urec, part, (float4*)d_out, cnt, nsp_pad);
}

// Round 4
// 21.823 us; speedup vs baseline: 2.7506x; 1.1873x over previous
//
#include <hip/hip_runtime.h>
#include <math.h>

#define HW 128
#define EPSF 1e-4f
#define L2E 1.4426950408889634f
#define NPART 16            // partial-groups
#define WPB 8               // waves per accum block
#define NGROUPS (NPART * WPB)   // 128 splat groups
#define NP 8                // pixel rows per lane
#define NUNI 6              // per-splat uniforms: u1, s, col0..3 (2^-96-scaled)
#define DLT (1.0f / HW)
#define SHIFTF 96.0f        // exponent pre-bias folded into qc (colors scaled 2^-96)
#define CSCALE 0x1p-96f
#define DCLAMP 18.0f        // per-row log2-step clamp (R <= 2^18; clamp only under-estimates)

typedef float f2 __attribute__((ext_vector_type(2)));

__device__ __forceinline__ float ex2(float x) {        // 2^x
    float r; asm("v_exp_f32 %0, %1" : "=v"(r) : "v"(x)); return r;
}
__device__ __forceinline__ float rcp_(float x) {       // 1/x
    float r; asm("v_rcp_f32 %0, %1" : "=v"(r) : "v"(x)); return r;
}
__device__ __forceinline__ float fsig(float x) {       // sigmoid
    return rcp_(1.0f + ex2(-L2E * x));
}
__device__ __forceinline__ float ftanh(float x) {      // tanh = 1 - 2/(e^2x+1)
    return 1.0f - 2.0f * rcp_(1.0f + ex2((2.0f * L2E) * x));
}

// One WAVE per splat (4 splats / 256-thr block). Computes polynomial coeffs
// of z*log2e = u0 x^2 + u1 y^2 + u2 xy + u3 x + u4 y + u5 (logdet/log2pi
// cancel in exp(k - k.max())), grid max m via per-column y-vertex, stores
//   tab[n][col] = (qb, qc - m + 96),  qb = u2 x + u4,  qc = (u0 x + u3)x + u5
// and 6 per-splat uniforms SoA-blocked per splat-group for accum s_load:
//   urec[g*spw*6 + {0..5}*spw + o] = {u1, s=2^(2 u1 DLT^2), c0..c3 * 2^-96}
// The +96 bias / 2^-96 color scale keep accum's exponent-space row
// recurrence in normal-f32 range: z' <= 96 everywhere (global max m), and
// any column whose band-start underflows (z0' < -126) can rise at most
// 7*DCLAMP=126 -> stays < 0 biased = < 2^-96 unbiased = negligible.
// Pad splats (n >= n_splats): qc' = -16384 -> W = 0; s = 1.
__global__ __launch_bounds__(256) void splat_setup_max(
    const float* __restrict__ rho, const float* __restrict__ sigma,
    const float* __restrict__ coords, const float* __restrict__ alpha,
    const float* __restrict__ colors, const float* __restrict__ tm,
    float2* __restrict__ tab, float* __restrict__ urec,
    int n_splats, int nsp_pad)
{
    const int lane = threadIdx.x & 63;
    const int n = blockIdx.x * 4 + (threadIdx.x >> 6);
    if (n >= nsp_pad) return;

    const int spw = nsp_pad >> 7;              // nsp_pad / NGROUPS
    const int g   = n / spw;
    const int o   = n - g * spw;
    float* ub = urec + (size_t)g * spw * NUNI;

    if (n >= n_splats) {                       // zero-contribution pad record
        tab[(size_t)n * HW + lane]      = make_float2(0.0f, -16384.0f);
        tab[(size_t)n * HW + 64 + lane] = make_float2(0.0f, -16384.0f);
        if (lane == 0) {
            ub[0 * spw + o] = 0.0f;            // u1
            ub[1 * spw + o] = 1.0f;            // s (irrelevant: W0 = 0)
#pragma unroll
            for (int i = 2; i < NUNI; ++i) ub[i * spw + o] = 0.0f;
        }
        return;
    }

    float T[16];
#pragma unroll
    for (int i = 0; i < 16; ++i) T[i] = tm[i];

    const float a  = fsig(alpha[n]);
    const float r  = fsig(rho[n]) + EPSF;
    const float s0 = fsig(-sigma[n * 3 + 0]);
    const float s1 = fsig(-sigma[n * 3 + 1]);
    const float s2 = fsig(-sigma[n * 3 + 2]);
    const float sx = T[0] * s0 + T[1] * s1 + T[2]  * s2 + T[3];
    const float sy = T[4] * s0 + T[5] * s1 + T[6]  * s2 + T[7];
    const float sz = T[8] * s0 + T[9] * s1 + T[10] * s2 + T[11];

    const float c0 = ftanh(coords[n * 3 + 0]) + 0.5f;
    const float c1 = ftanh(coords[n * 3 + 1]) + 0.5f;
    const float c2 = ftanh(coords[n * 3 + 2]) + 0.5f;
    const float cx = T[0] * c0 + T[1] * c1 + T[2]  * c2 + T[3];
    const float cy = T[4] * c0 + T[5] * c1 + T[6]  * c2 + T[7];
    const float cz = T[8] * c0 + T[9] * c1 + T[10] * c2 + T[11];

    const float col0 = ftanh(colors[n * 4 + 0] * a);
    const float col1 = ftanh(colors[n * 4 + 1] * a);
    const float col2 = ftanh(colors[n * 4 + 2] * a);
    const float col3 = ftanh(colors[n * 4 + 3] * a);

    const float M00 = sx * sx + EPSF, M01 = sx * sy * r, M02 = sx * sz * r;
    const float M11 = sy * sy + EPSF, M12 = sy * sz * r, M22 = sz * sz + EPSF;

    const float C00 = M11 * M22 - M12 * M12;
    const float C01 = M02 * M12 - M01 * M22;
    const float C02 = M01 * M12 - M02 * M11;
    const float det = M00 * C00 + M01 * C01 + M02 * C02;
    const float idet = -0.5f / det;
    const float A00 = C00 * idet;
    const float A01 = C01 * idet;
    const float A02 = C02 * idet;
    const float A11 = (M00 * M22 - M02 * M02) * idet;
    const float A12 = (M01 * M02 - M00 * M12) * idet;
    const float A22 = (M00 * M11 - M01 * M01) * idet;

    const float pz = cz + 1.0f;
    const float u0 = A00 * L2E;
    const float u1 = A11 * L2E;                 // < 0 (SPD cov)
    const float u2 = 2.0f * A01 * L2E;
    const float u3 = 2.0f * (A00 * cx + A01 * cy + A02 * pz) * L2E;
    const float u4 = 2.0f * (A01 * cx + A11 * cy + A12 * pz) * L2E;
    const float u5 = (A00 * cx * cx + A11 * cy * cy + A22 * pz * pz
                      + 2.0f * (A01 * cx * cy + A02 * cx * pz + A12 * cy * pz)) * L2E;

    float qbv[2], qcv[2];
    float m = -INFINITY;
#pragma unroll
    for (int cc = 0; cc < 2; ++cc) {
        const int colx = lane + 64 * cc;
        const float x  = (float)colx * (1.0f / HW);
        const float qb = fmaf(u2, x, u4);
        const float qc = fmaf(fmaf(u0, x, u3), x, u5);
        qbv[cc] = qb; qcv[cc] = qc;
        const float yv = -qb * 0.5f * rcp_(u1);
        int iy = (int)rintf(yv * (float)HW);
        iy = max(1, min(HW - 2, iy));
        const int cand[5] = {0, HW - 1, iy - 1, iy, iy + 1};
#pragma unroll
        for (int q = 0; q < 5; ++q) {
            const float y = (float)cand[q] * (1.0f / HW);
            m = fmaxf(m, fmaf(fmaf(u1, y, qb), y, qc));
        }
    }
#pragma unroll
    for (int off = 32; off > 0; off >>= 1)
        m = fmaxf(m, __shfl_xor(m, off, 64));

    tab[(size_t)n * HW + lane]      = make_float2(qbv[0], qcv[0] - m + SHIFTF);
    tab[(size_t)n * HW + 64 + lane] = make_float2(qbv[1], qcv[1] - m + SHIFTF);
    if (lane == 0) {
        ub[0 * spw + o] = u1;
        ub[1 * spw + o] = ex2(u1 * (2.0f * DLT * DLT));   // row-ratio ratio s
        ub[2 * spw + o] = col0 * CSCALE;
        ub[3 * spw + o] = col1 * CSCALE;
        ub[4 * spw + o] = col2 * CSCALE;
        ub[5 * spw + o] = col3 * CSCALE;
    }
}

// 512 blocks (32 pixel-tiles x 16 partial-groups) x 512 thr (8 waves),
// launch_bounds(512,4) -> 4 waves/SIMD, 32 KB LDS, 2 blocks/CU — SAME
// occupancy/grid/LDS as the proven 20.9us version. Only the inner math
// changes: exponent-space row recurrence. z(y) is quadratic in y with
// constant 2nd difference c = 2*u1*DLT^2, so down a column:
//   W_{k+1} = W_k * R_k,  R_{k+1} = R_k * s,  s = exp2(c) (uniform)
// => 2 v_exp per splat-lane (8 px) instead of 8 (trans pipe was 57% of
// issue). d0 clamped <= 18: clamp only under-estimates (computed z <=
// true z <= 96 biased), so no overflow and error <= ~2^-17. Validated
// numerics (r1: passed, absmax identical). Tail + combine unchanged.
__global__ __launch_bounds__(512, 4) void splat_accum(
    const float2* __restrict__ tab, const float* __restrict__ urec,
    float4* __restrict__ part, int nsp_pad)
{
    __shared__ float4 lred[4][NP][64];        // 32 KB

    const int t    = threadIdx.x;
    const int lane = t & 63;
    const int w    = __builtin_amdgcn_readfirstlane(t >> 6);   // wave 0..7
    const int tile = blockIdx.x >> 4;         // 0..31
    const int pg   = blockIdx.x & 15;         // partial-group
    const int g    = pg * WPB + w;            // splat group 0..127 (scalar)

    const int ch      = tile & 1;
    const int rowBand = tile >> 1;            // 0..15
    const int col     = ch * 64 + lane;

    const float y0   = (float)(rowBand * NP) * DLT;   // band first row
    const float y0sq = y0 * y0;
    const float k0   = DLT * (2.0f * y0 + DLT);       // d0 = qb*DLT + u1*k0

    const int spw = nsp_pad >> 7;             // 16 for N=2048
    const int j0  = g * spw;

    f2 acc[4][NP / 2];                        // [channel][row-pair]
#pragma unroll
    for (int c = 0; c < 4; ++c)
#pragma unroll
        for (int i = 0; i < NP / 2; ++i) acc[c][i] = (f2){0.0f, 0.0f};

    const f2*    tp = (const f2*)(tab + (size_t)j0 * HW + col);
    const float* gb = urec + (size_t)g * spw * NUNI;   // uniform (scalar) ptr

    if (spw == 16) {
        float su1[16], ssj[16], sc0[16], sc1[16], sc2[16], sc3[16];
#pragma unroll
        for (int j = 0; j < 16; ++j) {
            su1[j] = gb[j];
            ssj[j] = gb[16 + j];
            sc0[j] = gb[32 + j];
            sc1[j] = gb[48 + j];
            sc2[j] = gb[64 + j];
            sc3[j] = gb[80 + j];
        }
#pragma unroll
        for (int j = 0; j < 16; ++j) {
            const f2 q = tp[(size_t)j * HW];            // (qb, qc')
            float z0 = fmaf(su1[j], y0sq, q.y);
            z0 = fmaf(q.x, y0, z0);                     // z at band row 0
            float d0 = fmaf(su1[j], k0, q.x * DLT);     // first fwd difference
            d0 = fminf(d0, DCLAMP);
            float W = ex2(z0);
            float R = ex2(d0);
            float wr[NP];
            wr[0] = W;
#pragma unroll
            for (int k = 1; k < NP; ++k) {
                W = W * R; R = R * ssj[j];
                wr[k] = W;
            }
#pragma unroll
            for (int i = 0; i < NP / 2; ++i) {
                const f2 w2 = (f2){wr[2 * i], wr[2 * i + 1]};
                acc[0][i] = w2 * sc0[j] + acc[0][i];    // pk_fma, uniform bcast
                acc[1][i] = w2 * sc1[j] + acc[1][i];
                acc[2][i] = w2 * sc2[j] + acc[2][i];
                acc[3][i] = w2 * sc3[j] + acc[3][i];
            }
        }
    } else {
        for (int j = 0; j < spw; ++j) {
            const f2 q = tp[(size_t)j * HW];
            const float u1j = gb[j];
            const float sj  = gb[spw + j];
            const float c0j = gb[2 * spw + j];
            const float c1j = gb[3 * spw + j];
            const float c2j = gb[4 * spw + j];
            const float c3j = gb[5 * spw + j];
            float z0 = fmaf(u1j, y0sq, q.y);
            z0 = fmaf(q.x, y0, z0);
            float d0 = fmaf(u1j, k0, q.x * DLT);
            d0 = fminf(d0, DCLAMP);
            float W = ex2(z0);
            float R = ex2(d0);
            float wr[NP];
            wr[0] = W;
#pragma unroll
            for (int k = 1; k < NP; ++k) {
                W = W * R; R = R * sj;
                wr[k] = W;
            }
#pragma unroll
            for (int i = 0; i < NP / 2; ++i) {
                const f2 w2 = (f2){wr[2 * i], wr[2 * i + 1]};
                acc[0][i] = w2 * c0j + acc[0][i];
                acc[1][i] = w2 * c1j + acc[1][i];
                acc[2][i] = w2 * c2j + acc[2][i];
                acc[3][i] = w2 * c3j + acc[3][i];
            }
        }
    }

    // unpack to per-pixel float4 for the reduction tail
    float4 vout[NP];
#pragma unroll
    for (int p = 0; p < NP; ++p) {
        const int i = p >> 1;
        if (p & 1) vout[p] = make_float4(acc[0][i].y, acc[1][i].y, acc[2][i].y, acc[3][i].y);
        else       vout[p] = make_float4(acc[0][i].x, acc[1][i].x, acc[2][i].x, acc[3][i].x);
    }

    // 3-round tree: 8 waves -> 1
    if (w >= 4) {
#pragma unroll
        for (int p = 0; p < NP; ++p) lred[w - 4][p][lane] = vout[p];
    }
    __syncthreads();
    if (w < 4) {
#pragma unroll
        for (int p = 0; p < NP; ++p) {
            const float4 v = lred[w][p][lane];
            vout[p].x += v.x; vout[p].y += v.y; vout[p].z += v.z; vout[p].w += v.w;
        }
    }
    __syncthreads();
    if (w == 2 || w == 3) {
#pragma unroll
        for (int p = 0; p < NP; ++p) lred[w - 2][p][lane] = vout[p];
    }
    __syncthreads();
    if (w < 2) {
#pragma unroll
        for (int p = 0; p < NP; ++p) {
            const float4 v = lred[w][p][lane];
            vout[p].x += v.x; vout[p].y += v.y; vout[p].z += v.z; vout[p].w += v.w;
        }
    }
    __syncthreads();
    if (w == 1) {
#pragma unroll
        for (int p = 0; p < NP; ++p) lred[0][p][lane] = vout[p];
    }
    __syncthreads();
    if (w == 0) {
#pragma unroll
        for (int p = 0; p < NP; ++p) {
            const float4 v = lred[0][p][lane];
            vout[p].x += v.x; vout[p].y += v.y; vout[p].z += v.z; vout[p].w += v.w;
            part[(size_t)pg * (HW * HW) + (rowBand * NP + p) * HW + col] = vout[p];
        }
    }
}

// out[pix] = sum of the NPART partials
__global__ __launch_bounds__(256) void splat_combine(
    const float4* __restrict__ part, float4* __restrict__ out)
{
    const int i = blockIdx.x * 256 + threadIdx.x;
    float4 s = part[i];
#pragma unroll
    for (int gg = 1; gg < NPART; ++gg) {
        const float4 v = part[(size_t)gg * (HW * HW) + i];
        s.x += v.x; s.y += v.y; s.z += v.z; s.w += v.w;
    }
    out[i] = s;
}

extern "C" void kernel_launch(void* const* d_in, const int* in_sizes, int n_in,
                              void* d_out, int out_size, void* d_ws, size_t ws_size,
                              hipStream_t stream) {
    const float* rho    = (const float*)d_in[0];
    const float* sigma  = (const float*)d_in[1];
    const float* coords = (const float*)d_in[2];
    const float* alpha  = (const float*)d_in[3];
    const float* colors = (const float*)d_in[4];
    const float* tm     = (const float*)d_in[5];

    const int n_splats = in_sizes[0];
    const int nsp_pad  = (n_splats + 511) & ~511;   // %512==0

    // workspace layout (256 B aligned):
    //   tab  : nsp_pad * 128 * float2
    //   urec : nsp_pad * 6 * float (SoA-blocked per group)
    //   part : NPART * 16384 * float4
    char* wsb = (char*)d_ws;
    float2* tab = (float2*)wsb;
    size_t off = ((size_t)nsp_pad * HW * sizeof(float2) + 255) & ~(size_t)255;
    float* urec = (float*)(wsb + off);
    off = (off + (size_t)nsp_pad * NUNI * sizeof(float) + 255) & ~(size_t)255;
    float4* part = (float4*)(wsb + off);

    splat_setup_max<<<nsp_pad / 4, 256, 0, stream>>>(
        rho, sigma, coords, alpha, colors, tm, tab, urec, n_splats, nsp_pad);
    splat_accum<<<32 * NPART, 512, 0, stream>>>(tab, urec, part, nsp_pad);
    splat_combine<<<(HW * HW) / 256, 256, 0, stream>>>(part, (float4*)d_out);
}

// Round 5
// 20.998 us; speedup vs baseline: 2.8587x; 1.0393x over previous
//
#include <hip/hip_runtime.h>
#include <math.h>

#define HW 128
#define EPSF 1e-4f
#define L2E 1.4426950408889634f
#define NPART 16            // partial-groups
#define WPB 8               // waves per accum block
#define NGROUPS (NPART * WPB)   // 128 splat groups
#define NP 8                // pixel rows per lane

typedef float f2 __attribute__((ext_vector_type(2)));

__device__ __forceinline__ float ex2(float x) {        // 2^x
    float r; asm("v_exp_f32 %0, %1" : "=v"(r) : "v"(x)); return r;
}
__device__ __forceinline__ float rcp_(float x) {       // 1/x
    float r; asm("v_rcp_f32 %0, %1" : "=v"(r) : "v"(x)); return r;
}
__device__ __forceinline__ float fsig(float x) {       // sigmoid
    return rcp_(1.0f + ex2(-L2E * x));
}
__device__ __forceinline__ float ftanh(float x) {      // tanh = 1 - 2/(e^2x+1)
    return 1.0f - 2.0f * rcp_(1.0f + ex2((2.0f * L2E) * x));
}

// One WAVE per splat (4 splats / 256-thr block). Computes polynomial coeffs
// of z*log2e = u0 x^2 + u1 y^2 + u2 xy + u3 x + u4 y + u5 (logdet/log2pi
// cancel in exp(k - k.max())), grid max m via per-column y-vertex, stores
//   tab[n][col] = (qb, qc - m),  qb = u2 x + u4,  qc = (u0 x + u3)x + u5
// and 5 per-splat uniforms SoA-blocked per splat-group for accum s_load:
//   urec[g*spw*5 + {0..4}*spw + o] = {u1, c0, c1, c2, c3}
// Pad splats (n >= n_splats): qc' = -16384 -> exp2 == 0, uniforms = 0.
__global__ __launch_bounds__(256) void splat_setup_max(
    const float* __restrict__ rho, const float* __restrict__ sigma,
    const float* __restrict__ coords, const float* __restrict__ alpha,
    const float* __restrict__ colors, const float* __restrict__ tm,
    float2* __restrict__ tab, float* __restrict__ urec,
    int n_splats, int nsp_pad)
{
    const int lane = threadIdx.x & 63;
    const int n = blockIdx.x * 4 + (threadIdx.x >> 6);
    if (n >= nsp_pad) return;

    const int spw = nsp_pad >> 7;              // nsp_pad / NGROUPS
    const int g   = n / spw;
    const int o   = n - g * spw;
    float* ub = urec + (size_t)g * spw * 5;

    if (n >= n_splats) {                       // zero-contribution pad record
        tab[(size_t)n * HW + lane]      = make_float2(0.0f, -16384.0f);
        tab[(size_t)n * HW + 64 + lane] = make_float2(0.0f, -16384.0f);
        if (lane == 0) {
#pragma unroll
            for (int i = 0; i < 5; ++i) ub[i * spw + o] = 0.0f;
        }
        return;
    }

    float T[16];
#pragma unroll
    for (int i = 0; i < 16; ++i) T[i] = tm[i];

    const float a  = fsig(alpha[n]);
    const float r  = fsig(rho[n]) + EPSF;
    const float s0 = fsig(-sigma[n * 3 + 0]);
    const float s1 = fsig(-sigma[n * 3 + 1]);
    const float s2 = fsig(-sigma[n * 3 + 2]);
    const float sx = T[0] * s0 + T[1] * s1 + T[2]  * s2 + T[3];
    const float sy = T[4] * s0 + T[5] * s1 + T[6]  * s2 + T[7];
    const float sz = T[8] * s0 + T[9] * s1 + T[10] * s2 + T[11];

    const float c0 = ftanh(coords[n * 3 + 0]) + 0.5f;
    const float c1 = ftanh(coords[n * 3 + 1]) + 0.5f;
    const float c2 = ftanh(coords[n * 3 + 2]) + 0.5f;
    const float cx = T[0] * c0 + T[1] * c1 + T[2]  * c2 + T[3];
    const float cy = T[4] * c0 + T[5] * c1 + T[6]  * c2 + T[7];
    const float cz = T[8] * c0 + T[9] * c1 + T[10] * c2 + T[11];

    const float col0 = ftanh(colors[n * 4 + 0] * a);
    const float col1 = ftanh(colors[n * 4 + 1] * a);
    const float col2 = ftanh(colors[n * 4 + 2] * a);
    const float col3 = ftanh(colors[n * 4 + 3] * a);

    const float M00 = sx * sx + EPSF, M01 = sx * sy * r, M02 = sx * sz * r;
    const float M11 = sy * sy + EPSF, M12 = sy * sz * r, M22 = sz * sz + EPSF;

    const float C00 = M11 * M22 - M12 * M12;
    const float C01 = M02 * M12 - M01 * M22;
    const float C02 = M01 * M12 - M02 * M11;
    const float det = M00 * C00 + M01 * C01 + M02 * C02;
    const float idet = -0.5f / det;
    const float A00 = C00 * idet;
    const float A01 = C01 * idet;
    const float A02 = C02 * idet;
    const float A11 = (M00 * M22 - M02 * M02) * idet;
    const float A12 = (M01 * M02 - M00 * M12) * idet;
    const float A22 = (M00 * M11 - M01 * M01) * idet;

    const float pz = cz + 1.0f;
    const float u0 = A00 * L2E;
    const float u1 = A11 * L2E;
    const float u2 = 2.0f * A01 * L2E;
    const float u3 = 2.0f * (A00 * cx + A01 * cy + A02 * pz) * L2E;
    const float u4 = 2.0f * (A01 * cx + A11 * cy + A12 * pz) * L2E;
    const float u5 = (A00 * cx * cx + A11 * cy * cy + A22 * pz * pz
                      + 2.0f * (A01 * cx * cy + A02 * cx * pz + A12 * cy * pz)) * L2E;

    float qbv[2], qcv[2];
    float m = -INFINITY;
#pragma unroll
    for (int cc = 0; cc < 2; ++cc) {
        const int colx = lane + 64 * cc;
        const float x  = (float)colx * (1.0f / HW);
        const float qb = fmaf(u2, x, u4);
        const float qc = fmaf(fmaf(u0, x, u3), x, u5);
        qbv[cc] = qb; qcv[cc] = qc;
        const float yv = -qb * 0.5f * rcp_(u1);
        int iy = (int)rintf(yv * (float)HW);
        iy = max(1, min(HW - 2, iy));
        const int cand[5] = {0, HW - 1, iy - 1, iy, iy + 1};
#pragma unroll
        for (int q = 0; q < 5; ++q) {
            const float y = (float)cand[q] * (1.0f / HW);
            m = fmaxf(m, fmaf(fmaf(u1, y, qb), y, qc));
        }
    }
#pragma unroll
    for (int off = 32; off > 0; off >>= 1)
        m = fmaxf(m, __shfl_xor(m, off, 64));

    tab[(size_t)n * HW + lane]      = make_float2(qbv[0], qcv[0] - m);
    tab[(size_t)n * HW + 64 + lane] = make_float2(qbv[1], qcv[1] - m);
    if (lane == 0) {
        ub[0 * spw + o] = u1;
        ub[1 * spw + o] = col0;
        ub[2 * spw + o] = col1;
        ub[3 * spw + o] = col2;
        ub[4 * spw + o] = col3;
    }
}

// 512 blocks (32 pixel-tiles x 16 partial-groups) x 512 thr (8 waves),
// launch_bounds(512,4) -> 4 waves/SIMD, VGPR <= 128. Tile: col-half
// ch = tile&1 (lane -> column ch*64+lane), row-band rb = tile>>1 (rows
// rb*8+{0..7}). Wave w streams splat group pg*8+w (16 splats). Uniforms
// hoisted to SGPRs before the loop. Inner loop: ONE coalesced per-lane
// dwordx2 tab load per splat feeding 8 pixels, and PACKED fp32 math
// (v_pk_fma_f32 on row-pairs; SGPR coefficients broadcast free in VOP3P):
// ~4.3 VALU ops/splat-pixel vs 7 scalar. acc layout [channel][row-pair]
// so the exp pair {wt0,wt1} is the packed multiplicand. Tail: 3-round
// LDS tree, partial store; combine sums NPART partials.
// NOTE (session ledger): pipe-balance at 4 waves/SIMD is max(VALU 192,
// trans 256) cyc/splat-step -> trans-bound; the exp-free row-recurrence
// variant rebalances to VALU 280 and measured SLOWER (R4: +0.9us). Fusion
// of combine via fence (R2: +39us) or sc1 write-through (R3: +5us) both
// lose to the dispatch boundary. This 3-kernel form is the optimum found.
__global__ __launch_bounds__(512, 4) void splat_accum(
    const float2* __restrict__ tab, const float* __restrict__ urec,
    float4* __restrict__ part, int nsp_pad)
{
    __shared__ float4 lred[4][NP][64];        // 32 KB

    const int t    = threadIdx.x;
    const int lane = t & 63;
    const int w    = __builtin_amdgcn_readfirstlane(t >> 6);   // wave 0..7
    const int tile = blockIdx.x >> 4;         // 0..31
    const int pg   = blockIdx.x & 15;         // partial-group
    const int g    = pg * WPB + w;            // splat group 0..127 (scalar)

    const int ch      = tile & 1;
    const int rowBand = tile >> 1;            // 0..15
    const int col     = ch * 64 + lane;

    f2 yv2[NP / 2], y22[NP / 2];
#pragma unroll
    for (int i = 0; i < NP / 2; ++i) {
        const float ya = (float)(rowBand * NP + 2 * i)     * (1.0f / HW);
        const float yb = (float)(rowBand * NP + 2 * i + 1) * (1.0f / HW);
        yv2[i] = (f2){ya, yb};
        y22[i] = (f2){ya * ya, yb * yb};
    }

    const int spw = nsp_pad >> 7;             // 16 for N=2048
    const int j0  = g * spw;

    f2 acc[4][NP / 2];                        // [channel][row-pair]
#pragma unroll
    for (int c = 0; c < 4; ++c)
#pragma unroll
        for (int i = 0; i < NP / 2; ++i) acc[c][i] = (f2){0.0f, 0.0f};

    const f2*    tp = (const f2*)(tab + (size_t)j0 * HW + col);
    const float* gb = urec + (size_t)g * spw * 5;   // uniform (scalar) ptr

    if (spw == 16) {
        float su1[16], sc0[16], sc1[16], sc2[16], sc3[16];
#pragma unroll
        for (int j = 0; j < 16; ++j) {
            su1[j] = gb[j];
            sc0[j] = gb[16 + j];
            sc1[j] = gb[32 + j];
            sc2[j] = gb[48 + j];
            sc3[j] = gb[64 + j];
        }
#pragma unroll
        for (int j = 0; j < 16; ++j) {
            const f2 q = tp[(size_t)j * HW];  // (qb, qc')
#pragma unroll
            for (int i = 0; i < NP / 2; ++i) {
                f2 z = su1[j] * y22[i] + q.y; // pk_fma, SGPR+bcast operands
                z = q.x * yv2[i] + z;         // pk_fma
                const f2 w2 = (f2){ex2(z.x), ex2(z.y)};
                acc[0][i] = w2 * sc0[j] + acc[0][i];   // pk_fma, SGPR bcast
                acc[1][i] = w2 * sc1[j] + acc[1][i];
                acc[2][i] = w2 * sc2[j] + acc[2][i];
                acc[3][i] = w2 * sc3[j] + acc[3][i];
            }
        }
    } else {
        for (int j = 0; j < spw; ++j) {
            const f2 q = tp[(size_t)j * HW];
            const float u1j = gb[j];
            const float c0j = gb[spw + j];
            const float c1j = gb[2 * spw + j];
            const float c2j = gb[3 * spw + j];
            const float c3j = gb[4 * spw + j];
#pragma unroll
            for (int i = 0; i < NP / 2; ++i) {
                f2 z = u1j * y22[i] + q.y;
                z = q.x * yv2[i] + z;
                const f2 w2 = (f2){ex2(z.x), ex2(z.y)};
                acc[0][i] = w2 * c0j + acc[0][i];
                acc[1][i] = w2 * c1j + acc[1][i];
                acc[2][i] = w2 * c2j + acc[2][i];
                acc[3][i] = w2 * c3j + acc[3][i];
            }
        }
    }

    // unpack to per-pixel float4 for the reduction tail
    float4 vout[NP];
#pragma unroll
    for (int p = 0; p < NP; ++p) {
        const int i = p >> 1;
        if (p & 1) vout[p] = make_float4(acc[0][i].y, acc[1][i].y, acc[2][i].y, acc[3][i].y);
        else       vout[p] = make_float4(acc[0][i].x, acc[1][i].x, acc[2][i].x, acc[3][i].x);
    }

    // 3-round tree: 8 waves -> 1
    if (w >= 4) {
#pragma unroll
        for (int p = 0; p < NP; ++p) lred[w - 4][p][lane] = vout[p];
    }
    __syncthreads();
    if (w < 4) {
#pragma unroll
        for (int p = 0; p < NP; ++p) {
            const float4 v = lred[w][p][lane];
            vout[p].x += v.x; vout[p].y += v.y; vout[p].z += v.z; vout[p].w += v.w;
        }
    }
    __syncthreads();
    if (w == 2 || w == 3) {
#pragma unroll
        for (int p = 0; p < NP; ++p) lred[w - 2][p][lane] = vout[p];
    }
    __syncthreads();
    if (w < 2) {
#pragma unroll
        for (int p = 0; p < NP; ++p) {
            const float4 v = lred[w][p][lane];
            vout[p].x += v.x; vout[p].y += v.y; vout[p].z += v.z; vout[p].w += v.w;
        }
    }
    __syncthreads();
    if (w == 1) {
#pragma unroll
        for (int p = 0; p < NP; ++p) lred[0][p][lane] = vout[p];
    }
    __syncthreads();
    if (w == 0) {
#pragma unroll
        for (int p = 0; p < NP; ++p) {
            const float4 v = lred[0][p][lane];
            vout[p].x += v.x; vout[p].y += v.y; vout[p].z += v.z; vout[p].w += v.w;
            part[(size_t)pg * (HW * HW) + (rowBand * NP + p) * HW + col] = vout[p];
        }
    }
}

// out[pix] = sum of the NPART partials
__global__ __launch_bounds__(256) void splat_combine(
    const float4* __restrict__ part, float4* __restrict__ out)
{
    const int i = blockIdx.x * 256 + threadIdx.x;
    float4 s = part[i];
#pragma unroll
    for (int gg = 1; gg < NPART; ++gg) {
        const float4 v = part[(size_t)gg * (HW * HW) + i];
        s.x += v.x; s.y += v.y; s.z += v.z; s.w += v.w;
    }
    out[i] = s;
}

extern "C" void kernel_launch(void* const* d_in, const int* in_sizes, int n_in,
                              void* d_out, int out_size, void* d_ws, size_t ws_size,
                              hipStream_t stream) {
    const float* rho    = (const float*)d_in[0];
    const float* sigma  = (const float*)d_in[1];
    const float* coords = (const float*)d_in[2];
    const float* alpha  = (const float*)d_in[3];
    const float* colors = (const float*)d_in[4];
    const float* tm     = (const float*)d_in[5];

    const int n_splats = in_sizes[0];
    const int nsp_pad  = (n_splats + 511) & ~511;   // %512==0

    // workspace layout (256 B aligned):
    //   tab  : nsp_pad * 128 * float2
    //   urec : nsp_pad * 5 * float (SoA-blocked per group)
    //   part : NPART * 16384 * float4
    char* wsb = (char*)d_ws;
    float2* tab = (float2*)wsb;
    size_t off = ((size_t)nsp_pad * HW * sizeof(float2) + 255) & ~(size_t)255;
    float* urec = (float*)(wsb + off);
    off = (off + (size_t)nsp_pad * 5 * sizeof(float) + 255) & ~(size_t)255;
    float4* part = (float4*)(wsb + off);

    splat_setup_max<<<nsp_pad / 4, 256, 0, stream>>>(
        rho, sigma, coords, alpha, colors, tm, tab, urec, n_splats, nsp_pad);
    splat_accum<<<32 * NPART, 512, 0, stream>>>(tab, urec, part, nsp_pad);
    splat_combine<<<(HW * HW) / 256, 256, 0, stream>>>(part, (float4*)d_out);
}